// Round 1
// baseline (243.855 us; speedup 1.0000x reference)
//
#include <hip/hip_runtime.h>

// y[..., 2k]   = T[k][0][0]*x[2k] + T[k][0][1]*x[2k+1]
// y[..., 2k+1] = T[k][1][0]*x[2k] + T[k][1][1]*x[2k+1]
//
// Contiguous grid-stride sweep (fill-kernel-like): 2048 blocks x 256 threads
// = 524288 threads, each owning one float4 (= twiddle pairs 2p, 2p+1).
// Grid stride 524288 float4 is a multiple of the 1024-float4 row, so each
// thread's column p = gid % 1024 is iteration-invariant -> twiddles load
// exactly once into registers. Per iteration the whole grid touches one
// contiguous 8 MiB window -> DRAM-friendly sequential stream.
// Plain loads for x (L2/L3 may serve part of it); nontemporal stores for y
// (write-once, avoid cache pollution). 8 loads in flight per thread.

typedef float f4 __attribute__((ext_vector_type(4)));

#define NTHR  256
#define NBLK  2048
#define SPAN  (NBLK * NTHR)   // 524288 float4 = 8 MiB per sweep; % 1024 == 0
#define BATCH 8

__global__ __launch_bounds__(NTHR) void butterfly_kernel(
    const f4* __restrict__ x,
    const f4* __restrict__ tw,   // tw[k] = {t00,t01,t10,t11} for pair k
    f4* __restrict__ y,
    int niter)                   // total_f4 / SPAN, multiple of BATCH
{
    const int gid = blockIdx.x * NTHR + threadIdx.x;   // [0, SPAN)
    const int p   = gid & 1023;                         // float4 column in row

    const f4 t0 = tw[2 * p];
    const f4 t1 = tw[2 * p + 1];

    const f4* xp = x + gid;
    f4*       yp = y + gid;

    for (int it = 0; it < niter; it += BATCH) {
        f4 xv[BATCH];
#pragma unroll
        for (int i = 0; i < BATCH; ++i)
            xv[i] = xp[(size_t)(it + i) * SPAN];

#pragma unroll
        for (int i = 0; i < BATCH; ++i) {
            f4 yv;
            yv.x = t0.x * xv[i].x + t0.y * xv[i].y;
            yv.y = t0.z * xv[i].x + t0.w * xv[i].y;
            yv.z = t1.x * xv[i].z + t1.y * xv[i].w;
            yv.w = t1.z * xv[i].z + t1.w * xv[i].w;
            __builtin_nontemporal_store(yv, yp + (size_t)(it + i) * SPAN);
        }
    }
}

extern "C" void kernel_launch(void* const* d_in, const int* in_sizes, int n_in,
                              void* d_out, int out_size, void* d_ws, size_t ws_size,
                              hipStream_t stream) {
    const f4* x  = (const f4*)d_in[0];   // (4, 2048, 4096) fp32
    const f4* tw = (const f4*)d_in[1];   // (2048, 2, 2) fp32
    f4* y = (f4*)d_out;

    const int total_f4 = out_size / 4;   // out_size in floats; 8388608 f4
    const int niter    = total_f4 / SPAN; // 16

    butterfly_kernel<<<dim3(NBLK), dim3(NTHR), 0, stream>>>(x, tw, y, niter);
}

// Round 2
// 226.947 us; speedup vs baseline: 1.0745x; 1.0745x over previous
//
#include <hip/hip_runtime.h>

// y[..., 2k]   = T[k][0][0]*x[2k] + T[k][0][1]*x[2k+1]
// y[..., 2k+1] = T[k][1][0]*x[2k] + T[k][1][1]*x[2k+1]
//
// R0 structure (proven fastest so far): each thread owns one float4-column p,
// loads its two twiddle float4s once, streams 8 rows. All 8 x-loads are
// batched up front (fully unrolled -> compiler keeps them in flight; VGPR
// ~50, still <=64 so full 32 waves/CU).
//
// R1 lesson: grid-stride sweep collapsed MLP (VGPR=28) -> 2.2 TB/s. Revert.
// R1 lesson 2: plain (cached) x-loads let the 256 MB Infinity Cache serve
// ~half the input (FETCH_SIZE halved) -> keep plain loads.
// New isolation this round: PLAIN stores instead of nontemporal. The fill
// kernel (plain stores) hits 6.7 TB/s; both NT-store variants sat at
// 2.2-3.7 TB/s. Theory: NT stores bypass L2 and stall waves on the HBM
// controller; plain stores retire into L2 (34.5 TB/s) and drain async.

typedef float f4 __attribute__((ext_vector_type(4)));

#define ROW4 1024            // 4096 floats / 4 per row
#define ROWS_PER_BLOCK 8

__global__ __launch_bounds__(256) void butterfly_kernel(
    const f4* __restrict__ x,
    const f4* __restrict__ tw,   // tw[k] = {t00,t01,t10,t11} for pair k
    f4* __restrict__ y)
{
    const int p  = blockIdx.x * 256 + threadIdx.x;   // float4 column [0,1024)
    const int r0 = blockIdx.y * ROWS_PER_BLOCK;

    const f4 t0 = tw[2 * p];
    const f4 t1 = tw[2 * p + 1];

    const f4* xp = x + (size_t)r0 * ROW4 + p;
    f4*       yp = y + (size_t)r0 * ROW4 + p;

    f4 xv[ROWS_PER_BLOCK];
#pragma unroll
    for (int r = 0; r < ROWS_PER_BLOCK; ++r)
        xv[r] = xp[(size_t)r * ROW4];

#pragma unroll
    for (int r = 0; r < ROWS_PER_BLOCK; ++r) {
        f4 yv;
        yv.x = t0.x * xv[r].x + t0.y * xv[r].y;
        yv.y = t0.z * xv[r].x + t0.w * xv[r].y;
        yv.z = t1.x * xv[r].z + t1.y * xv[r].w;
        yv.w = t1.z * xv[r].z + t1.w * xv[r].w;
        yp[(size_t)r * ROW4] = yv;
    }
}

extern "C" void kernel_launch(void* const* d_in, const int* in_sizes, int n_in,
                              void* d_out, int out_size, void* d_ws, size_t ws_size,
                              hipStream_t stream) {
    const f4* x  = (const f4*)d_in[0];   // (4, 2048, 4096) fp32
    const f4* tw = (const f4*)d_in[1];   // (2048, 2, 2) fp32
    f4* y = (f4*)d_out;

    const int n_rows = out_size / 4096;  // 8192

    dim3 block(256);
    dim3 grid(ROW4 / 256, n_rows / ROWS_PER_BLOCK);  // (4, 1024) = 4096 blocks
    butterfly_kernel<<<grid, block, 0, stream>>>(x, tw, y);
}